// Round 1
// baseline (145.937 us; speedup 1.0000x reference)
//
#include <hip/hip_runtime.h>
#include <hip/hip_bf16.h>

#define NB 8        // batches
#define SS 4096
#define DD 1024
#define MROWS 4095   // valid delta rows per batch
#define MT 33        // m-tiles per batch (stride 127)
#define MPAD 4224    // 33*128
#define BK 64

typedef __attribute__((ext_vector_type(8))) short short8;
typedef __attribute__((ext_vector_type(4))) float f32x4;

// ---- ws layout (bytes) ----
// [0, 2 MB)            : Wb   bf16 [1024][1024]
// [2 MB, +69206016)    : Delta bf16 [8][4224][1024]
// then pn f32 [8][4224][8], pc f32 [8][4224][8]
#define WB_OFF    0
#define DL_OFF    2097152
#define PN_OFF    (2097152 + 69206016)          // 71303168
#define PC_OFF    (PN_OFF + 8*4224*8*4)         // +1081344

__device__ __forceinline__ unsigned short f2bf(float f) {
    union { float f; unsigned int u; } v; v.f = f;
    unsigned int r = v.u + 0x7FFFu + ((v.u >> 16) & 1u);   // RNE
    return (unsigned short)(r >> 16);
}
__device__ __forceinline__ float bf2f(unsigned short u) {
    union { unsigned int u; float f; } v; v.u = ((unsigned int)u) << 16;
    return v.f;
}

// ---- pass 0: W -> bf16 ----
__global__ void conv_w(const float* __restrict__ W, unsigned short* __restrict__ Wb) {
    int i = (blockIdx.x * 256 + threadIdx.x) * 4;   // 1M elems, 4/thread
    float4 a = *(const float4*)(W + i);
    ushort4 o;
    o.x = f2bf(a.x); o.y = f2bf(a.y); o.z = f2bf(a.z); o.w = f2bf(a.w);
    *(ushort4*)(Wb + i) = o;
}

// ---- pass 1: Delta = x[r+1]-x[r] -> bf16, zero-pad rows 4095..4223 ----
__global__ void conv_delta(const float* __restrict__ x, unsigned short* __restrict__ dl) {
    int tid = blockIdx.x * 256 + threadIdx.x;       // 8*4224*256 threads
    int b   = tid / (4224 * 256);
    int rem = tid - b * (4224 * 256);
    int row = rem >> 8;
    int d0  = (rem & 255) * 4;
    ushort4 o;
    if (row < MROWS) {
        const float* p = x + ((size_t)b * SS + row) * DD + d0;
        float4 a = *(const float4*)p;
        float4 c = *(const float4*)(p + DD);
        o.x = f2bf(c.x - a.x); o.y = f2bf(c.y - a.y);
        o.z = f2bf(c.z - a.z); o.w = f2bf(c.w - a.w);
    } else {
        o.x = o.y = o.z = o.w = 0;
    }
    *(ushort4*)(dl + ((size_t)b * MPAD + row) * DD + d0) = o;
}

// ---- pass 2: GEMM Y = Delta @ W^T (bf16 MFMA), fused row-norm / adj-dot ----
// grid: (8 n-tiles, 33 m-tiles, 8 batches), block 256 (4 waves, 2x2)
__launch_bounds__(256, 2)
__global__ void gemm_nc(const unsigned short* __restrict__ dl,
                        const unsigned short* __restrict__ Wb,
                        float* __restrict__ pn, float* __restrict__ pc) {
    __shared__ __align__(16) char smem[34816];
    unsigned short* Alds = (unsigned short*)smem;            // swizzled [128][64]
    unsigned short* Blds = (unsigned short*)(smem + 16384);  // swizzled [128][64]

    const int t = threadIdx.x;
    const int bn = blockIdx.x;        // 0..7
    const int mt = blockIdx.y;        // 0..32
    const int b  = blockIdx.z;
    const int m0 = mt * 127;          // 1-row overlap between m-tiles
    const int lane = t & 63, w = t >> 6;
    const int wr = w >> 1, wc = w & 1;
    const int lrow = lane & 15, lgrp = lane >> 4;

    const unsigned short* Abase = dl + ((size_t)b * MPAD + m0) * DD;
    const unsigned short* Bbase = Wb + (size_t)bn * 128 * DD;

    f32x4 acc[4][4] = {};

    for (int kt = 0; kt < 16; ++kt) {
        const int k0 = kt * BK;
        __syncthreads();
        #pragma unroll
        for (int it = 0; it < 4; ++it) {
            int off = it * 2048 + t * 8;      // element offset in 128x64 tile
            int row = off >> 6, col = off & 63;
            uint4 av = *(const uint4*)(Abase + (size_t)row * DD + k0 + col);
            uint4 bv = *(const uint4*)(Bbase + (size_t)row * DD + k0 + col);
            int sa = (col >> 3) ^ (row & 7);  // XOR swizzle, 16B slots
            *(uint4*)((char*)Alds + row * 128 + sa * 16) = av;
            *(uint4*)((char*)Blds + row * 128 + sa * 16) = bv;
        }
        __syncthreads();
        #pragma unroll
        for (int kk = 0; kk < 2; ++kk) {
            short8 af[4], bfr[4];
            #pragma unroll
            for (int m = 0; m < 4; ++m) {
                int row = wr * 64 + m * 16 + lrow;
                int s = (kk * 4 + lgrp) ^ (row & 7);
                af[m] = *(const short8*)((const char*)Alds + row * 128 + s * 16);
            }
            #pragma unroll
            for (int n = 0; n < 4; ++n) {
                int row = wc * 64 + n * 16 + lrow;
                int s = (kk * 4 + lgrp) ^ (row & 7);
                bfr[n] = *(const short8*)((const char*)Blds + row * 128 + s * 16);
            }
            #pragma unroll
            for (int m = 0; m < 4; ++m)
                #pragma unroll
                for (int n = 0; n < 4; ++n)
                    acc[m][n] = __builtin_amdgcn_mfma_f32_16x16x32_bf16(
                        af[m], bfr[n], acc[m][n], 0, 0, 0);
        }
    }

    // epilogue: Y tile -> LDS as bf16 [128][136]
    __syncthreads();
    unsigned short* Ylds = (unsigned short*)smem;
    #pragma unroll
    for (int m = 0; m < 4; ++m) {
        int rbase = wr * 64 + m * 16 + lgrp * 4;   // C/D: row=(lane>>4)*4+reg
        #pragma unroll
        for (int n = 0; n < 4; ++n) {
            int col = wc * 64 + n * 16 + lrow;     // C/D: col=lane&15
            #pragma unroll
            for (int j = 0; j < 4; ++j)
                Ylds[(rbase + j) * 136 + col] = f2bf(acc[m][n][j]);
        }
    }
    __syncthreads();

    // reduce: thread -> (row r = t>>1, half h = t&1), 64 cols each
    int r = t >> 1, h = t & 1;
    const unsigned short* yr  = Ylds + r * 136 + h * 64;
    const unsigned short* yr1 = yr + 136;
    bool do_c = (r < 127);
    float sn = 0.f, sc = 0.f;
    #pragma unroll
    for (int c8 = 0; c8 < 8; ++c8) {
        short8 v = *(const short8*)(yr + c8 * 8);
        short8 v1 = {0,0,0,0,0,0,0,0};
        if (do_c) v1 = *(const short8*)(yr1 + c8 * 8);
        #pragma unroll
        for (int j = 0; j < 8; ++j) {
            float y = bf2f((unsigned short)v[j]);
            sn += y * y;
            sc += y * bf2f((unsigned short)v1[j]);
        }
    }
    sn += __shfl_xor(sn, 1);
    sc += __shfl_xor(sc, 1);
    if (h == 0 && r < 127) {
        size_t base = ((size_t)b * MPAD + (m0 + r)) * 8 + bn;
        pn[base] = sn;
        pc[base] = sc;
    }
}

// ---- pass 3: combine partials -> scores -> adj ----
__global__ void score_k(const float* __restrict__ pn, const float* __restrict__ pc,
                        const float* __restrict__ gate, float* __restrict__ out) {
    int tid = blockIdx.x * 256 + threadIdx.x;
    const int total = NB * 4094;
    if (tid >= total) return;
    int b = tid / 4094;
    int i = tid - b * 4094;
    const float* pnb = pn + (size_t)b * MPAD * 8;
    const float* pcb = pc + (size_t)b * MPAD * 8;
    float n0 = 0.f, n1 = 0.f, c0 = 0.f;
    #pragma unroll
    for (int j = 0; j < 8; ++j) {
        n0 += pnb[(size_t)i * 8 + j];
        n1 += pnb[(size_t)(i + 1) * 8 + j];
        c0 += pcb[(size_t)i * 8 + j];
    }
    float d1a = sqrtf(fmaxf(n0, 0.f));
    float d1b = sqrtf(fmaxf(n1, 0.f));
    float d2  = sqrtf(fmaxf(n0 + 2.f * c0 + n1, 0.f));
    float path = d1a + d1b;
    float s = 1.f - (path - d2) / fmaxf(d2, 1e-6f);
    s = fmaxf(s, 0.f);
    float g = gate[0] * 0.5f;
    float adj = g * (s * (1.f / 4094.f) - 0.5f) * 0.1f;
    out[(size_t)b * SS + i + 1] = adj;
    if (i == 0) {
        float e = g * (-0.5f) * 0.1f;
        out[(size_t)b * SS] = e;
        out[(size_t)b * SS + SS - 1] = e;
    }
}

extern "C" void kernel_launch(void* const* d_in, const int* in_sizes, int n_in,
                              void* d_out, int out_size, void* d_ws, size_t ws_size,
                              hipStream_t stream) {
    const float* x    = (const float*)d_in[0];
    const float* W    = (const float*)d_in[1];
    // d_in[2] (bias) cancels in all distances -> unused
    const float* gate = (const float*)d_in[3];
    float* out = (float*)d_out;
    char* ws = (char*)d_ws;

    unsigned short* Wb = (unsigned short*)(ws + WB_OFF);
    unsigned short* dl = (unsigned short*)(ws + DL_OFF);
    float* pn = (float*)(ws + PN_OFF);
    float* pc = (float*)(ws + PC_OFF);

    conv_w<<<1024, 256, 0, stream>>>(W, Wb);
    conv_delta<<<NB * 4224, 256, 0, stream>>>(x, dl);   // 33792 blocks, 4 elems/thread
    dim3 g(8, MT, NB);
    gemm_nc<<<g, 256, 0, stream>>>(dl, Wb, pn, pc);
    score_k<<<(NB * 4094 + 255) / 256, 256, 0, stream>>>(pn, pc, gate, out);
}